// Round 5
// baseline (492.160 us; speedup 1.0000x reference)
//
#include <hip/hip_runtime.h>

// LSTM: B=2048, T=512, I=6, H=50, O=3. fp32 in/out, bf16 MFMA inner matmul.
//
// R5: SINGLE-WAVE WORKGROUPS, ZERO BARRIERS. R1/R3/R4 (4-wave WGs, 1
// barrier/step) all plateau at ~1300-1500 cyc/step regardless of structure:
// the barrier-coupled chain (3 LDS round trips + cross-SIMD barrier + full
// lgkm drain) is the wall, and co-resident WGs convoy in phase. Fix: one
// wave per WG, one batch row per wave (NB=1, grid=2048, block=64). A wave's
// own LDS ops are in-order, so the whole recurrence needs NO __syncthreads:
// frag read -> 13x2 MFMA -> masked Gs scatter -> Gs read -> act -> h write
// -> next frag read, with fine-grained lgkmcnt. 8 independent chains/CU
// (2 waves/SIMD) that never synchronize.
//
// Layout (as R4): A-vector k-map [x(6)|1|0|h(50)|0pad], gate permutation
// j' = 4*hidx + gate so lane (col,quad) tile ti holds gates (i,f,g,o) of
// (b=col, hidx=4*ti+quad) in its f32x4 acc (C-layout col=lane&15,
// row=quad*4+reg). Only col==0 is real (all B cols read row 0 -> broadcast);
// col==0 lanes scatter gates to Gs[hidx], lane L<52 reads pair hidx=L.

#define L2E 1.44269504088896340736f

typedef float  f32x4 __attribute__((ext_vector_type(4)));
typedef short  s16x8 __attribute__((ext_vector_type(8)));   // 8 bf16 bit-patterns

__device__ __forceinline__ float fast_exp2(float x){ return __builtin_amdgcn_exp2f(x); }
__device__ __forceinline__ float fast_rcp (float x){ return __builtin_amdgcn_rcpf(x); }
__device__ __forceinline__ float sigm (float x){ return fast_rcp(1.0f + fast_exp2(-L2E * x)); }
__device__ __forceinline__ float tanhf_(float x){ return 1.0f - 2.0f * fast_rcp(1.0f + fast_exp2((2.0f*L2E) * x)); }

// float -> bf16 bits, round-to-nearest-even
__device__ __forceinline__ unsigned short f2bf(float f){
  unsigned u = __builtin_bit_cast(unsigned, f);
  u = (u + 0x7FFFu + ((u >> 16) & 1u)) >> 16;
  return (unsigned short)u;
}

constexpr int B_ = 2048, T_ = 512, I_ = 6, H_ = 50;
constexpr int NT = 13;              // j' tiles: 13*16 = 208 >= 200

__global__ __launch_bounds__(64, 2)
void lstm_kernel(const float* __restrict__ x,
                 const float* __restrict__ W_ih, const float* __restrict__ W_hh,
                 const float* __restrict__ b_ih, const float* __restrict__ b_hh,
                 const float* __restrict__ W_out, const float* __restrict__ b_out,
                 float* __restrict__ out)
{
  __shared__ unsigned short Xq[T_ * 8 + 8];  // [x_t(6)|1|0] bf16, all t (8.2 KB)
  __shared__ unsigned short Hb[64];          // h(50) bf16 + zero pad
  __shared__ float Gsf[64 * 4];              // gate scratch: slot L = f32x4 at L*4

  const int lane = threadIdx.x;    // 0..63 (one wave)
  const int col  = lane & 15;      // MFMA N index (only col 0 real)
  const int quad = lane >> 4;      // MFMA row-group / k-group
  const int b    = blockIdx.x;     // batch row

  // ---- stage this row's x into Xq as [x|1|0] 16B slices (one-time) ----
  {
    const float* xrow = x + (size_t)b * (T_ * I_);
    #pragma unroll
    for (int i = 0; i < 8; i++) {
      const int t = i * 64 + lane;
      const float2 a0 = *(const float2*)(xrow + t * 6);
      const float2 a1 = *(const float2*)(xrow + t * 6 + 2);
      const float2 a2 = *(const float2*)(xrow + t * 6 + 4);
      s16x8 v;
      v[0] = (short)f2bf(a0.x); v[1] = (short)f2bf(a0.y);
      v[2] = (short)f2bf(a1.x); v[3] = (short)f2bf(a1.y);
      v[4] = (short)f2bf(a2.x); v[5] = (short)f2bf(a2.y);
      v[6] = (short)0x3F80;     v[7] = 0;
      *(s16x8*)&Xq[t * 8] = v;
    }
  }
  Hb[lane] = 0;   // h0 = 0; entries 50..63 stay 0 forever (zero k-pad)

  // ---- weight fragments (A-operand, once; 104 VGPRs). k-map:
  // k<6: W_ih[.,k]; k==6: bias; k==7: 0; 8<=k<58: W_hh[.,k-8]; else 0
  s16x8 wfrag[NT][2];
  #pragma unroll
  for (int ti = 0; ti < NT; ti++) {
    const int jp = ti * 16 + col;
    const int hh = jp >> 2, gsel = jp & 3;
    const int r  = gsel * 50 + hh;
    #pragma unroll
    for (int kh = 0; kh < 2; kh++) {
      s16x8 w;
      #pragma unroll
      for (int kk = 0; kk < 8; kk++) {
        const int k = kh * 32 + quad * 8 + kk;
        float v = 0.0f;
        if (jp < 200) {
          if      (k < 6)            v = W_ih[r * 6 + k];
          else if (k == 6)           v = b_ih[r] + b_hh[r];
          else if (k >= 8 && k < 58) v = W_hh[r * 50 + (k - 8)];
        }
        w[kk] = (short)f2bf(v);
      }
      wfrag[ti][kh] = w;
    }
  }

  // per-lane B-frag pointers (t-invariant part)
  const unsigned short* h0p = &Hb[quad ? quad * 8 - 8 : 0];  // frag0, quad>0
  const unsigned short* h1p = &Hb[24 + quad * 8];            // frag1 (48..55 = pad)

  float c_   = 0.0f;
  float hreg = 0.0f;

  // ---- recurrence: no barriers; same-wave LDS ordering is the sync ----
  for (int t = 0; t < T_; t++) {
    const s16x8 bfr0 = *(const s16x8*)(quad == 0 ? (const unsigned short*)&Xq[t * 8] : h0p);
    const s16x8 bfr1 = *(const s16x8*)h1p;

    #pragma unroll
    for (int ti = 0; ti < NT; ti++) {
      f32x4 a = {0.f, 0.f, 0.f, 0.f};
      a = __builtin_amdgcn_mfma_f32_16x16x32_bf16(wfrag[ti][0], bfr0, a, 0, 0, 0);
      a = __builtin_amdgcn_mfma_f32_16x16x32_bf16(wfrag[ti][1], bfr1, a, 0, 0, 0);
      if (col == 0) *(f32x4*)&Gsf[(4 * ti + quad) * 4] = a;   // slot hidx=4ti+quad
    }

    // lane L handles pair hidx=L (L<52 valid; j'>=200 rows are zero-weighted)
    const f32x4 g = *(const f32x4*)&Gsf[lane * 4];
    const float gi = sigm (g[0]);
    const float gf = sigm (g[1]);
    const float gg = tanhf_(g[2]);
    const float go = sigm (g[3]);
    c_ = gf * c_ + gi * gg;
    const float hn = go * tanhf_(c_);
    hreg = hn;
    if (lane < H_) Hb[lane] = f2bf(hn);   // next frag read (same wave) sees this
  }

  // ---- epilogue: logits + softmax (reuse Gsf as fp32 scratch) ----
  if (lane < H_) Gsf[lane] = hreg;
  if (lane < 3) {
    float s = b_out[lane];
    for (int k = 0; k < H_; k++) s += W_out[lane * H_ + k] * Gsf[k];
    Gsf[60 + lane] = s;
  }
  const float l0 = Gsf[60], l1 = Gsf[61], l2 = Gsf[62];
  if (lane < 3) {
    const float m  = fmaxf(l0, fmaxf(l1, l2));
    const float e0 = fast_exp2((l0 - m) * L2E);
    const float e1 = fast_exp2((l1 - m) * L2E);
    const float e2 = fast_exp2((l2 - m) * L2E);
    const float inv = fast_rcp(e0 + e1 + e2);
    const float e   = (lane == 0) ? e0 : (lane == 1) ? e1 : e2;
    out[(size_t)b * 3 + lane] = e * inv;
  }
}

extern "C" void kernel_launch(void* const* d_in, const int* in_sizes, int n_in,
                              void* d_out, int out_size, void* d_ws, size_t ws_size,
                              hipStream_t stream) {
  const float* x     = (const float*)d_in[0];
  const float* W_ih  = (const float*)d_in[1];
  const float* W_hh  = (const float*)d_in[2];
  const float* b_ih  = (const float*)d_in[3];
  const float* b_hh  = (const float*)d_in[4];
  const float* W_out = (const float*)d_in[5];
  const float* b_out = (const float*)d_in[6];
  lstm_kernel<<<B_, 64, 0, stream>>>(x, W_ih, W_hh, b_ih, b_hh,
                                     W_out, b_out, (float*)d_out);
}

// Round 7
// 447.105 us; speedup vs baseline: 1.1008x; 1.1008x over previous
//
#include <hip/hip_runtime.h>

// LSTM: B=2048, T=512, I=6, H=50, O=3. fp32 in/out, bf16 MFMA inner matmul.
//
// R7 = R6 + x-feed fix. R6's two-anti-phase-chain pipeline was numerically
// mis-fed: xqrow was group-RELATIVE (row = col&3) so group B's MFMA read
// group A's x rows (absmax 4.3e-2). The x base pointer is now a PHASE
// parameter (xqA = Xq[row], xqB = Xq[4+row]), mirroring the h base.
//
// Structure (R6): 1 WG/CU (grid=256, 256 thr), 8 rows = group A (0-3) +
// B (4-7), half-step offset. Phase 1: MFMA_A(t) + act_B(t-1); barrier.
// Phase 2: MFMA_B(t) + act_A(t); barrier. Each chain's ~500-cyc serial path
// spans 2 phases while the other chain supplies issue work; zero-init Gs is
// exactly the h0=c0=0 state so no prologue. Evidence: R1/R3/R4 showed the
// barrier-coupled chain is the wall (~1500 cyc/step, TLP-invariant); R5
// showed per-row MFMA replication swamps (MfmaUtil 40%).
//
// Layout (verified R4/R5): A-vector k-map [x(6)|1|0|h(50)|0pad]; gate
// permutation j'=4*hidx+gate so lane (col,quad) tile ti holds (i,f,g,o) of
// (row=col&3, hidx=4*(wave+4*ti)+quad). Masked Gs scatter (col<4) + merged
// read: every lane activates exactly one cell per phase.

#define L2E 1.44269504088896340736f

typedef float  f32x4 __attribute__((ext_vector_type(4)));
typedef short  s16x8 __attribute__((ext_vector_type(8)));   // 8 bf16 bit-patterns

__device__ __forceinline__ float fast_exp2(float x){ return __builtin_amdgcn_exp2f(x); }
__device__ __forceinline__ float fast_rcp (float x){ return __builtin_amdgcn_rcpf(x); }
__device__ __forceinline__ float sigm (float x){ return fast_rcp(1.0f + fast_exp2(-L2E * x)); }
__device__ __forceinline__ float tanhf_(float x){ return 1.0f - 2.0f * fast_rcp(1.0f + fast_exp2((2.0f*L2E) * x)); }

// float -> bf16 bits, round-to-nearest-even
__device__ __forceinline__ unsigned short f2bf(float f){
  unsigned u = __builtin_bit_cast(unsigned, f);
  u = (u + 0x7FFFu + ((u >> 16) & 1u)) >> 16;
  return (unsigned short)u;
}

constexpr int B_ = 2048, T_ = 512, I_ = 6, H_ = 50;
constexpr int NB  = 8;            // rows per WG (grid=256 -> 1 WG/CU)
constexpr int XQP = T_ * 8 + 8;   // Xq row pitch in shorts (16B slices, pad)
constexpr int HP  = 80;           // Hb row pitch in shorts (160 B)
constexpr int NT  = 13;           // j' tiles: 13*16 = 208 >= 200

__global__ __launch_bounds__(256, 1)
void lstm_kernel(const float* __restrict__ x,
                 const float* __restrict__ W_ih, const float* __restrict__ W_hh,
                 const float* __restrict__ b_ih, const float* __restrict__ b_hh,
                 const float* __restrict__ W_out, const float* __restrict__ b_out,
                 float* __restrict__ out)
{
  __shared__ __align__(16) unsigned short Xq[NB][XQP]; // [x|1|0] bf16, all t (65.7 KB)
  __shared__ __align__(16) unsigned short Hb[2][4][HP];// [group][row][h+0pad]
  __shared__ f32x4 Gs[2][4][64];                       // [group][wave][slot]
  __shared__ float Hlast[NB][H_];

  const int tid  = threadIdx.x;
  const int lane = tid & 63;
  const int wave = tid >> 6;
  const int col  = lane & 15;   // MFMA N index; rows 0-3 real, 4-15 replicas
  const int quad = lane >> 4;   // MFMA k/row-group
  const int row  = col & 3;     // group-local batch row this lane feeds
  const int b0   = blockIdx.x * NB;

  // merged-cell identity: slot L = mb + 4*q + 16*tt
  const int mb = lane & 3;
  const int mh = 4 * (wave + 4 * (lane >> 4)) + ((lane >> 2) & 3);

  // ---- stage x -> Xq bf16 [x(6)|1|0] 16B slices (one-time) ----
  for (int idx = tid; idx < NB * T_; idx += 256) {
    const int r = idx >> 9, t = idx & (T_ - 1);
    const float* xp = x + ((size_t)(b0 + r) * T_ + t) * I_;
    const float2 a0 = *(const float2*)xp;
    const float2 a1 = *(const float2*)(xp + 2);
    const float2 a2 = *(const float2*)(xp + 4);
    s16x8 v;
    v[0] = (short)f2bf(a0.x); v[1] = (short)f2bf(a0.y);
    v[2] = (short)f2bf(a1.x); v[3] = (short)f2bf(a1.y);
    v[4] = (short)f2bf(a2.x); v[5] = (short)f2bf(a2.y);
    v[6] = (short)0x3F80;     v[7] = 0;
    *(s16x8*)&Xq[r][t * 8] = v;
  }
  // ---- zero Hb (h0=0, pads stay 0) and Gs (== exact zero initial state) ----
  for (int i = tid; i < 2 * 4 * HP; i += 256) (&Hb[0][0][0])[i] = 0;
  {
    float* gz = (float*)&Gs[0][0][0];
    for (int i = tid; i < 2 * 4 * 64 * 4; i += 256) gz[i] = 0.0f;
  }

  // ---- weight fragments (A-operand, once). k-map:
  // k<6: W_ih[.,k]; k==6: bias; k==7: 0; 8<=k<58: W_hh[.,k-8]; else 0
  s16x8 wfrag[4][2];
  #pragma unroll
  for (int ti = 0; ti < 4; ti++) {
    const int jt = wave + 4 * ti;           // wave-uniform
    if (jt < NT) {
      const int jp = jt * 16 + col;
      const int hh = jp >> 2, gsel = jp & 3;
      const int r  = gsel * 50 + hh;
      #pragma unroll
      for (int kh = 0; kh < 2; kh++) {
        s16x8 w;
        #pragma unroll
        for (int kk = 0; kk < 8; kk++) {
          const int k = kh * 32 + quad * 8 + kk;
          float v = 0.0f;
          if (jp < 200) {
            if      (k < 6)            v = W_ih[r * 6 + k];
            else if (k == 6)           v = b_ih[r] + b_hh[r];
            else if (k >= 8 && k < 58) v = W_hh[r * 50 + (k - 8)];
          }
          w[kk] = (short)f2bf(v);
        }
        wfrag[ti][kh] = w;
      }
    }
  }

  // ---- t-invariant pointers ----
  const unsigned short* xqA = &Xq[row][0];       // group A: batch rows 0-3
  const unsigned short* xqB = &Xq[4 + row][0];   // group B: batch rows 4-7
  const int f0h = row * HP + (quad ? quad * 8 - 8 : 0);  // frag0 h-slice (quad>0)
  const int f1h = row * HP + 24 + quad * 8;              // frag1 h-slice
  const unsigned short* hA = &Hb[0][0][0];
  const unsigned short* hB = &Hb[1][0][0];
  f32x4* gsA = &Gs[0][wave][0];
  f32x4* gsB = &Gs[1][wave][0];

  float cA = 0.f, cB = 0.f, hrA = 0.f, hrB = 0.f;

  __syncthreads();

  // one phase: MFMA for group g (reads xq[t] + hrd), gates -> gw;
  // activations for the OTHER group from gr (written last phase, same wave),
  // h -> hwr. One barrier after (caller).
  auto PHASE = [&](int t, const unsigned short* xq, const unsigned short* hrd,
                   f32x4* gw, const f32x4* gr,
                   float& c_, float& hr_, unsigned short* hwr) {
    const s16x8 bfr0 = *(const s16x8*)(quad == 0 ? xq + t * 8 : hrd + f0h);
    const s16x8 bfr1 = *(const s16x8*)(hrd + f1h);

    #pragma unroll
    for (int ti = 0; ti < 4; ti++) {
      const int jt = wave + 4 * ti;
      if (jt < NT) {
        f32x4 a = {0.f, 0.f, 0.f, 0.f};
        a = __builtin_amdgcn_mfma_f32_16x16x32_bf16(wfrag[ti][0], bfr0, a, 0, 0, 0);
        a = __builtin_amdgcn_mfma_f32_16x16x32_bf16(wfrag[ti][1], bfr1, a, 0, 0, 0);
        if (col < 4) gw[col + 4 * quad + 16 * ti] = a;
      }
    }

    const f32x4 g = gr[lane];          // other group's gates (last phase)
    const float gi = sigm (g[0]);
    const float gf = sigm (g[1]);
    const float gg = tanhf_(g[2]);
    const float go = sigm (g[3]);
    c_ = gf * c_ + gi * gg;
    const float hn = go * tanhf_(c_);
    hr_ = hn;
    if (mh < H_) hwr[mb * HP + mh] = f2bf(hn);
  };

  for (int t = 0; t < T_; t++) {
    PHASE(t, xqA, hA, gsA, gsB, cB, hrB, (unsigned short*)hB); // MFMA_A(t), act_B(t-1)
    __syncthreads();
    PHASE(t, xqB, hB, gsB, gsA, cA, hrA, (unsigned short*)hA); // MFMA_B(t), act_A(t)
    __syncthreads();
  }
  // drain the pipeline: act_B(511) (gates in gsB, same-wave, in-order)
  {
    const f32x4 g = gsB[lane];
    const float gi = sigm (g[0]);
    const float gf = sigm (g[1]);
    const float gg = tanhf_(g[2]);
    const float go = sigm (g[3]);
    cB = gf * cB + gi * gg;
    hrB = go * tanhf_(cB);
  }

  // ---- epilogue: logits + softmax for 8 rows ----
  if (mh < H_) { Hlast[mb][mh] = hrA; Hlast[4 + mb][mh] = hrB; }
  __syncthreads();

  if (tid < NB) {
    float l[3];
    #pragma unroll
    for (int o = 0; o < 3; o++) {
      float s = b_out[o];
      for (int k = 0; k < H_; k++) s += W_out[o * H_ + k] * Hlast[tid][k];
      l[o] = s;
    }
    const float m  = fmaxf(l[0], fmaxf(l[1], l[2]));
    const float e0 = fast_exp2((l[0] - m) * L2E);
    const float e1 = fast_exp2((l[1] - m) * L2E);
    const float e2 = fast_exp2((l[2] - m) * L2E);
    const float inv = fast_rcp(e0 + e1 + e2);
    float* op = out + (size_t)(b0 + tid) * 3;
    op[0] = e0 * inv; op[1] = e1 * inv; op[2] = e2 * inv;
  }
}

extern "C" void kernel_launch(void* const* d_in, const int* in_sizes, int n_in,
                              void* d_out, int out_size, void* d_ws, size_t ws_size,
                              hipStream_t stream) {
  const float* x     = (const float*)d_in[0];
  const float* W_ih  = (const float*)d_in[1];
  const float* W_hh  = (const float*)d_in[2];
  const float* b_ih  = (const float*)d_in[3];
  const float* b_hh  = (const float*)d_in[4];
  const float* W_out = (const float*)d_in[5];
  const float* b_out = (const float*)d_in[6];
  lstm_kernel<<<B_ / NB, 256, 0, stream>>>(x, W_ih, W_hh, b_ih, b_hh,
                                           W_out, b_out, (float*)d_out);
}